// Round 10
// baseline (124.287 us; speedup 1.0000x reference)
//
#include <hip/hip_runtime.h>
#include <cstdint>

namespace {

typedef _Float16 half2v __attribute__((ext_vector_type(2)));
typedef _Float16 half8 __attribute__((ext_vector_type(8)));
typedef float f32x4 __attribute__((ext_vector_type(4)));
typedef unsigned int u32x4 __attribute__((ext_vector_type(4)));

constexpr int KFS = 51;
constexpr int NB = 2, NC = 3, HH = 512, WW = 512;
constexpr int HP = HH + KFS - 1;   // 562
constexpr int WP = WW + KFS - 1;   // 562
constexpr size_t VSTR = (size_t)HH * WW;

constexpr int XCH = 32;              // output cols per block (2 n-tiles of 16)
constexpr int YR = 8;                // output rows per block
constexpr int NTHREADS = 512;        // 8 waves = 4 m-tiles x 2 n-tiles
constexpr int MR = 64;               // padded m-window (m>50 weight-zeroed)
constexpr int NROWS = YR + MR - 1;   // 71 staged in1 rows
constexpr int KDW = 52;              // LDS row stride in dwords (104 f16)
constexpr int AC = NROWS * KDW;      // dwords per channel A tile (3692)
constexpr int BSZ = 32 * KDW;        // dwords per B buffer (1664)

__device__ __forceinline__ uint32_t pack2(float a, float b) {
  half2v p;
  p.x = (_Float16)a;  // RNE
  p.y = (_Float16)b;
  return __builtin_bit_cast(uint32_t, p);
}

__global__ __launch_bounds__(NTHREADS, 2)
void sepconv_mfma(const float* __restrict__ in1, const float* __restrict__ in2,
                  const float* __restrict__ in3, float* __restrict__ out) {
  __shared__ uint32_t ALDS[NC * AC];   // 44,304 B: A[c][row][k] f16 pairs
  __shared__ uint32_t BLDS[2 * BSZ];   // 13,312 B: B[buf][n][k] f16 pairs
  __shared__ float RED[NC][4][XCH];    //  1,536 B: per-mtile partials

  const int t = threadIdx.x;
  const int lane = t & 63;
  const int wave = t >> 6;
  const int mt = wave & 3;   // m-tile (16 rows each)
  const int nt = wave >> 2;  // n-tile (16 cols each)
  const int l15 = lane & 15;
  const int lq = lane >> 4;

  const int x0 = blockIdx.x * XCH;
  const int y0 = blockIdx.y * YR;
  const int b = blockIdx.z;

  const float* in1b = in1 + (size_t)b * NC * HP * WP;
  const float* v2 = in2 + (size_t)b * KFS * VSTR;
  const float* h3 = in3 + (size_t)b * KFS * VSTR;

  // ---- Stage A once: A[c][r][k] = in1[c, y0+r, x0+k], k<82 valid, k>=82 zero.
  for (int u = t; u < NC * NROWS * 48; u += NTHREADS) {
    const int c = u / (NROWS * 48);
    const int rem = u - c * (NROWS * 48);
    const int r = rem / 48;
    const int kp = rem - r * 48;
    const int row = min(y0 + r, HP - 1);  // clamp; clamped rows weight-zeroed
    float2 g = make_float2(0.f, 0.f);
    if (kp < 41)  // pairs (0,1)..(80,81) valid; >=82 zero (B band never reaches)
      g = *reinterpret_cast<const float2*>(in1b + ((size_t)c * HP + row) * WP + x0 + 2 * kp);
    ALDS[c * AC + r * KDW + kp] = pack2(g.x, g.y);
  }

  // ---- B build for one y: B[n][k] = h[k-n, y, x0+n], zero outside band.
  auto buildB = [&](int y, int buf) {
    for (int u = t; u < 32 * 48; u += NTHREADS) {
      const int n = u / 48;
      const int kp = u - n * 48;
      const int j0 = 2 * kp - n;
      const float* hp = h3 + (size_t)y * WW + x0 + n;
      const float a = (j0 >= 0 && j0 < KFS) ? hp[(size_t)j0 * VSTR] : 0.f;
      const float bb = (j0 >= -1 && j0 + 1 < KFS) ? hp[(size_t)(j0 + 1) * VSTR] : 0.f;
      BLDS[buf * BSZ + n * KDW + kp] = pack2(a, bb);
    }
  };

  buildB(y0, 0);
  __syncthreads();

  for (int dy = 0; dy < YR; ++dy) {
    const int y = y0 + dy;
    const int buf = dy & 1;

    // Overlap next-y B build with this y's compute (disjoint LDS region).
    if (dy + 1 < YR) buildB(y + 1, buf ^ 1);

    // B fragments: n = nt*16 + l15, k = ks*32 + lq*8 + e (shared across c, m-tiles)
    u32x4 bf[3];
    #pragma unroll
    for (int ks = 0; ks < 3; ++ks)
      bf[ks] = *reinterpret_cast<const u32x4*>(
          &BLDS[buf * BSZ + (nt * 16 + l15) * KDW + ks * 16 + lq * 4]);

    // v weights for this wave's C-fragment rows (C: col=l15, row=lq*4+r)
    const int xg = x0 + nt * 16 + l15;
    float vw[4];
    #pragma unroll
    for (int r = 0; r < 4; ++r) {
      const int m = mt * 16 + lq * 4 + r;
      vw[r] = (m < KFS) ? v2[(size_t)m * VSTR + (size_t)y * WW + xg] : 0.f;
    }

    float psum[NC];
    #pragma unroll
    for (int c = 0; c < NC; ++c) {
      f32x4 acc = {0.f, 0.f, 0.f, 0.f};
      const int abase = c * AC + (dy + mt * 16 + l15) * KDW + lq * 4;
      #pragma unroll
      for (int ks = 0; ks < 3; ++ks) {
        const u32x4 af = *reinterpret_cast<const u32x4*>(&ALDS[abase + ks * 16]);
        acc = __builtin_amdgcn_mfma_f32_16x16x32_f16(
            __builtin_bit_cast(half8, af), __builtin_bit_cast(half8, bf[ks]),
            acc, 0, 0, 0);
      }
      float p = acc[0] * vw[0];
      p = fmaf(acc[1], vw[1], p);
      p = fmaf(acc[2], vw[2], p);
      p = fmaf(acc[3], vw[3], p);
      psum[c] = p;
    }

    // Column reduce across the 4 row-quarters of the fragment.
    #pragma unroll
    for (int c = 0; c < NC; ++c) {
      float p = psum[c];
      p += __shfl_xor(p, 16);
      p += __shfl_xor(p, 32);
      if (lane < 16) RED[c][mt][nt * 16 + l15] = p;
    }
    __syncthreads();

    // Final cross-m-tile sum + store (96 threads).
    if (t < NC * XCH) {
      const int c = t >> 5;
      const int xl = t & 31;
      const float o = RED[c][0][xl] + RED[c][1][xl] + RED[c][2][xl] + RED[c][3][xl];
      out[((size_t)(b * NC + c) * HH + y) * WW + x0 + xl] = o;
    }
    __syncthreads();
  }
}

}  // namespace

extern "C" void kernel_launch(void* const* d_in, const int* in_sizes, int n_in,
                              void* d_out, int out_size, void* d_ws, size_t ws_size,
                              hipStream_t stream) {
  const float* in1 = (const float*)d_in[0];
  const float* in2 = (const float*)d_in[1];
  const float* in3 = (const float*)d_in[2];
  float* out = (float*)d_out;

  dim3 grid(WW / XCH, HH / YR, NB);
  sepconv_mfma<<<grid, NTHREADS, 0, stream>>>(in1, in2, in3, out);
}

// Round 11
// 123.071 us; speedup vs baseline: 1.0099x; 1.0099x over previous
//
#include <hip/hip_runtime.h>
#include <cstdint>

namespace {

typedef _Float16 half2v __attribute__((ext_vector_type(2)));
typedef _Float16 half8 __attribute__((ext_vector_type(8)));
typedef float f32x4 __attribute__((ext_vector_type(4)));
typedef unsigned int u32x2 __attribute__((ext_vector_type(2)));
typedef unsigned int u32x4 __attribute__((ext_vector_type(4)));

constexpr int KFS = 51;
constexpr int NB = 2, NC = 3, HH = 512, WW = 512;
constexpr int HP = HH + KFS - 1;   // 562
constexpr int WP = WW + KFS - 1;   // 562
constexpr size_t VSTR = (size_t)HH * WW;

constexpr int XCH = 32;              // output cols per block (2 n-tiles)
constexpr int YR = 8;                // output rows per block
constexpr int NTHREADS = 512;        // 8 waves = 4 m-tiles x 2 n-tiles
constexpr int NROWS = YR + 64 - 1;   // 71 staged in1 rows
constexpr int KDW = 54;              // LDS row stride (54%32=22 -> <=2-way banks)
constexpr int AC = NROWS * KDW;      // 3834 dwords per channel A tile
constexpr int BSZ = 32 * KDW;        // 1728 dwords per B buffer
constexpr int SSTR = 54;             // h-slab per-n stride (f32); j at slot 1+j

__device__ __forceinline__ uint32_t pack2(float a, float b) {
  half2v p;
  p.x = (_Float16)a;  // RNE
  p.y = (_Float16)b;
  return __builtin_bit_cast(uint32_t, p);
}

__global__ __launch_bounds__(NTHREADS, 2)
void sepconv_mfma(const float* __restrict__ in1, const float* __restrict__ in2,
                  const float* __restrict__ in3, float* __restrict__ out) {
  __shared__ uint32_t ALDS[NC * AC];   // 46,008 B: A[c][row][k] f16 pairs
  __shared__ uint32_t BLDS[2 * BSZ];   // 13,824 B: B[buf][n][k] f16 pairs
  __shared__ float SB[32 * SSTR];      //  6,912 B: h-slab [n][1+j] f32
  __shared__ float RED[NC][4][XCH];    //  1,536 B

  const int t = threadIdx.x;
  const int lane = t & 63;
  const int wave = t >> 6;
  const int mt = wave & 3;   // m-tile
  const int nt = wave >> 2;  // n-tile
  const int l15 = lane & 15;
  const int lq = lane >> 4;

  const int x0 = blockIdx.x * XCH;
  const int y0 = blockIdx.y * YR;
  const int b = blockIdx.z;

  const float* in1b = in1 + (size_t)b * NC * HP * WP;
  const float* v2 = in2 + (size_t)b * KFS * VSTR;
  const float* h3 = in3 + (size_t)b * KFS * VSTR;

  // Coalesced h-slab stage: SB[n][1+j] = h[j, y, x0+n]  (lane-consecutive = n).
  auto stageSlab = [&](int y) {
    for (int u = t; u < KFS * 32; u += NTHREADS) {
      const int j = u >> 5;
      const int n = u & 31;
      SB[n * SSTR + 1 + j] = h3[(size_t)j * VSTR + (size_t)y * WW + x0 + n];
    }
  };

  // B build from slab: B[n][k] = h[k-n], clamped reads hit zero guard slots.
  auto buildB = [&](int buf) {
    for (int u = t; u < 32 * 48; u += NTHREADS) {
      const int n = u / 48;
      const int kp = u - n * 48;
      const int j0 = 2 * kp - n;
      const int ja = min(max(j0, -1), KFS);      // guard slots: -1 -> 0, 51 -> 52
      const int jb = min(max(j0 + 1, -1), KFS);
      const float a = SB[n * SSTR + 1 + ja];
      const float bb = SB[n * SSTR + 1 + jb];
      BLDS[buf * BSZ + n * KDW + kp] = pack2(a, bb);
    }
  };

  // Zero the slab guard slots (persist across all dy; data writes cover 1..51).
  if (t < 32) {
    SB[t * SSTR] = 0.f;
    SB[t * SSTR + 1 + KFS] = 0.f;
  }

  // Stage A once: A[c][r][k] = in1[c, y0+r, x0+k]; pairs >=41 zero.
  for (int u = t; u < NC * NROWS * 48; u += NTHREADS) {
    const int c = u / (NROWS * 48);
    const int rem = u - c * (NROWS * 48);
    const int r = rem / 48;
    const int kp = rem - r * 48;
    const int row = min(y0 + r, HP - 1);  // clamped rows are weight-zeroed
    float2 g = make_float2(0.f, 0.f);
    if (kp < 41)
      g = *reinterpret_cast<const float2*>(in1b + ((size_t)c * HP + row) * WP + x0 + 2 * kp);
    ALDS[c * AC + r * KDW + kp] = pack2(g.x, g.y);
  }

  stageSlab(y0);
  __syncthreads();
  buildB(0);
  __syncthreads();

  for (int dy = 0; dy < YR; ++dy) {
    const int y = y0 + dy;
    const int buf = dy & 1;

    // Coalesced slab stage for y+1 (consumed by buildB after the barrier).
    if (dy + 1 < YR) stageSlab(y + 1);

    // B fragments: n = nt*16+l15, k halfs = ks*32 + lq*8 + e  (2x b64, <=2-way)
    u32x4 bf[3];
    const int bbase = buf * BSZ + (nt * 16 + l15) * KDW;
    #pragma unroll
    for (int ks = 0; ks < 3; ++ks) {
      const u32x2 b0 = *reinterpret_cast<const u32x2*>(&BLDS[bbase + ks * 16 + lq * 4]);
      const u32x2 b1 = *reinterpret_cast<const u32x2*>(&BLDS[bbase + ks * 16 + lq * 4 + 2]);
      bf[ks] = u32x4{b0.x, b0.y, b1.x, b1.y};
    }

    // v weights for this wave's C rows (C: col=l15, row=lq*4+r)
    const int xg = x0 + nt * 16 + l15;
    float vw[4];
    #pragma unroll
    for (int r = 0; r < 4; ++r) {
      const int m = mt * 16 + lq * 4 + r;
      vw[r] = (m < KFS) ? v2[(size_t)m * VSTR + (size_t)y * WW + xg] : 0.f;
    }

    float psum[NC];
    #pragma unroll
    for (int c = 0; c < NC; ++c) {
      f32x4 acc = {0.f, 0.f, 0.f, 0.f};
      const int abase = c * AC + (dy + mt * 16 + l15) * KDW + lq * 4;
      #pragma unroll
      for (int ks = 0; ks < 3; ++ks) {
        const u32x2 a0 = *reinterpret_cast<const u32x2*>(&ALDS[abase + ks * 16]);
        const u32x2 a1 = *reinterpret_cast<const u32x2*>(&ALDS[abase + ks * 16 + 2]);
        const u32x4 af = u32x4{a0.x, a0.y, a1.x, a1.y};
        acc = __builtin_amdgcn_mfma_f32_16x16x32_f16(
            __builtin_bit_cast(half8, af), __builtin_bit_cast(half8, bf[ks]),
            acc, 0, 0, 0);
      }
      float p = acc[0] * vw[0];
      p = fmaf(acc[1], vw[1], p);
      p = fmaf(acc[2], vw[2], p);
      p = fmaf(acc[3], vw[3], p);
      psum[c] = p;
    }

    // Column reduce across the fragment's 4 row-quarters.
    #pragma unroll
    for (int c = 0; c < NC; ++c) {
      float p = psum[c];
      p += __shfl_xor(p, 16);
      p += __shfl_xor(p, 32);
      if (lane < 16) RED[c][mt][nt * 16 + l15] = p;
    }
    __syncthreads();  // RED ready; slab(y+1) ready

    if (dy + 1 < YR) buildB(buf ^ 1);

    if (t < NC * XCH) {
      const int c = t >> 5;
      const int xl = t & 31;
      const float o = RED[c][0][xl] + RED[c][1][xl] + RED[c][2][xl] + RED[c][3][xl];
      out[((size_t)(b * NC + c) * HH + y) * WW + x0 + xl] = o;
    }
    __syncthreads();  // BLDS[buf^1] ready; RED consumed
  }
}

}  // namespace

extern "C" void kernel_launch(void* const* d_in, const int* in_sizes, int n_in,
                              void* d_out, int out_size, void* d_ws, size_t ws_size,
                              hipStream_t stream) {
  const float* in1 = (const float*)d_in[0];
  const float* in2 = (const float*)d_in[1];
  const float* in3 = (const float*)d_in[2];
  float* out = (float*)d_out;

  dim3 grid(WW / XCH, HH / YR, NB);
  sepconv_mfma<<<grid, NTHREADS, 0, stream>>>(in1, in2, in3, out);
}

// Round 12
// 117.111 us; speedup vs baseline: 1.0613x; 1.0509x over previous
//
#include <hip/hip_runtime.h>
#include <cstdint>

namespace {

typedef _Float16 half2v __attribute__((ext_vector_type(2)));
typedef _Float16 half8 __attribute__((ext_vector_type(8)));
typedef float f32x4 __attribute__((ext_vector_type(4)));
typedef unsigned int u32x4 __attribute__((ext_vector_type(4)));

constexpr int KFS = 51;
constexpr int NB = 2, NC = 3, HH = 512, WW = 512;
constexpr int HP = HH + KFS - 1;   // 562
constexpr int WP = WW + KFS - 1;   // 562
constexpr size_t VSTR = (size_t)HH * WW;

constexpr int XCH = 32;              // output cols per block (2 n-tiles)
constexpr int YR = 8;                // output rows per block
constexpr int NTHREADS = 512;        // 8 waves = 4 m-tiles x 2 n-tiles
constexpr int NROWS = YR + 64 - 1;   // 71 staged in1 rows
constexpr int KDW = 52;              // row stride in dwords: 16B-aligned, <=2-way banks for b128
constexpr int AC = NROWS * KDW;      // 3692 dw per channel A tile
constexpr int BSZ = 32 * KDW;        // 1664 dw per B buffer
constexpr int SSTR = 54;             // h-slab per-n stride (f32); j at slot 1+j; guards at 0 and 52
constexpr int BU = 26;               // in-band B pack-units per n

__device__ __forceinline__ uint32_t pack2(float a, float b) {
  half2v p;
  p.x = (_Float16)a;  // RNE
  p.y = (_Float16)b;
  return __builtin_bit_cast(uint32_t, p);
}

__global__ __launch_bounds__(NTHREADS, 2)
void sepconv_mfma(const float* __restrict__ in1, const float* __restrict__ in2,
                  const float* __restrict__ in3, float* __restrict__ out) {
  __shared__ __align__(16) uint32_t ALDS[NC * AC];  // 44.3 KB
  __shared__ __align__(16) uint32_t BLDS[2 * BSZ];  // 13.3 KB
  __shared__ float SL[2][32 * SSTR];                // 13.8 KB h-slab, dbuf
  __shared__ float RED[2][NC][4][XCH];              //  3.0 KB, dbuf

  const int t = threadIdx.x;
  const int lane = t & 63;
  const int wave = t >> 6;
  const int mt = wave & 3;   // m-tile
  const int nt = wave >> 2;  // n-tile
  const int l15 = lane & 15;
  const int lq = lane >> 4;

  const int x0 = blockIdx.x * XCH;
  const int y0 = blockIdx.y * YR;
  const int b = blockIdx.z;

  const float* in1b = in1 + (size_t)b * NC * HP * WP;
  const float* v2 = in2 + (size_t)b * KFS * VSTR;
  const float* h3 = in3 + (size_t)b * KFS * VSTR;

  // ---- helpers -------------------------------------------------------------
  auto stageSlab = [&](int y, int sb) {
    for (int u = t; u < KFS * 32; u += NTHREADS) {
      const int j = u >> 5;
      const int n = u & 31;  // lane-consecutive n -> coalesced
      SL[sb][n * SSTR + 1 + j] = h3[(size_t)j * VSTR + (size_t)y * WW + x0 + n];
    }
  };

  // Band-only B build: B[n][kp] for kp = n/2 + s, s < 26 (26 units per n).
  auto buildB = [&](int sb, int bb) {
    for (int u = t; u < 32 * BU; u += NTHREADS) {
      const int n = u / BU;
      const int s = u - n * BU;
      const int kp = (n >> 1) + s;
      const int j0 = 2 * kp - n;            // in [-1, 50]
      const float* sp = &SL[sb][n * SSTR + 1];
      const float a = sp[j0];               // j0 = -1 hits zero guard
      const float bq = sp[j0 + 1];          // j0+1 = 51 hits zero guard (slot 52)
      BLDS[bb * BSZ + n * KDW + kp] = pack2(a, bq);
    }
  };

  auto loadVW = [&](int y, float (&vw)[4]) {
    const int xg = x0 + nt * 16 + l15;
    #pragma unroll
    for (int r = 0; r < 4; ++r) {
      const int m = mt * 16 + lq * 4 + r;
      vw[r] = (m < KFS) ? v2[(size_t)m * VSTR + (size_t)y * WW + xg] : 0.f;
    }
  };

  // ---- prologue ------------------------------------------------------------
  // Zero-fill BLDS (zero slots are y-invariant; band slots rewritten per y).
  for (int u = t; u < 2 * BSZ; u += NTHREADS) BLDS[u] = 0u;
  // Slab guards (slots 0 and 52 per n, both buffers).
  if (t < 64) {
    const int sb = t >> 5, n = t & 31;
    SL[sb][n * SSTR] = 0.f;
    SL[sb][n * SSTR + 52] = 0.f;
  }
  // Stage A once: A[c][r][kp] = in1[c, y0+r, x0+2kp..], kp<41 valid, rest zero.
  for (int u = t; u < NC * NROWS * 48; u += NTHREADS) {
    const int c = u / (NROWS * 48);
    const int rem = u - c * (NROWS * 48);
    const int r = rem / 48;
    const int kp = rem - r * 48;
    const int row = min(y0 + r, HP - 1);  // clamped rows are weight-zeroed
    float2 g = make_float2(0.f, 0.f);
    if (kp < 41)
      g = *reinterpret_cast<const float2*>(in1b + ((size_t)c * HP + row) * WP + x0 + 2 * kp);
    ALDS[(c * NROWS + r) * KDW + kp] = pack2(g.x, g.y);
  }
  stageSlab(y0, 0);
  float vw_cur[4];
  loadVW(y0, vw_cur);
  __syncthreads();                 // A, slab(y0), BLDS zeros, guards ready

  buildB(0, 0);                    // B(y0) -> BB[0]
  stageSlab(y0 + 1, 1);
  __syncthreads();                 // BB[0], SL[1] ready

  // ---- main loop: ONE barrier per dy --------------------------------------
  #pragma unroll 1
  for (int d = 0; d < YR; ++d) {
    const int y = y0 + d;
    const int cb = d & 1;

    // B fragments (b128): n = nt*16+l15, k-pairs ks*8.. (16 dw per ks chunk)
    const int bbase = cb * BSZ + (nt * 16 + l15) * KDW + lq * 4;
    u32x4 bf[3];
    #pragma unroll
    for (int ks = 0; ks < 3; ++ks)
      bf[ks] = *reinterpret_cast<const u32x4*>(&BLDS[bbase + ks * 16]);

    // prefetch v-weights for next dy (consumed after the barrier)
    float vw_next[4];
    if (d + 1 < YR) loadVW(y + 1, vw_next);

    // A fragments + MFMA (A row = d + m)
    float psum[NC];
    #pragma unroll
    for (int c = 0; c < NC; ++c) {
      f32x4 acc = {0.f, 0.f, 0.f, 0.f};
      const int abase = (c * NROWS + d + mt * 16 + l15) * KDW + lq * 4;
      #pragma unroll
      for (int ks = 0; ks < 3; ++ks) {
        const u32x4 af = *reinterpret_cast<const u32x4*>(&ALDS[abase + ks * 16]);
        acc = __builtin_amdgcn_mfma_f32_16x16x32_f16(
            __builtin_bit_cast(half8, af), __builtin_bit_cast(half8, bf[ks]),
            acc, 0, 0, 0);
      }
      float p = acc[0] * vw_cur[0];
      p = fmaf(acc[1], vw_cur[1], p);
      p = fmaf(acc[2], vw_cur[2], p);
      p = fmaf(acc[3], vw_cur[3], p);
      psum[c] = p;
    }

    // Column-reduce the fragment's 4 row-quarters -> RED[cb]
    #pragma unroll
    for (int c = 0; c < NC; ++c) {
      float p = psum[c];
      p += __shfl_xor(p, 16);
      p += __shfl_xor(p, 32);
      if (lane < 16) RED[cb][c][mt][nt * 16 + l15] = p;
    }

    // future-prep (overlaps with other waves' compute)
    if (d + 2 < YR) stageSlab(y + 2, cb);        // SL[cb] free: read last iter
    if (d + 1 < YR) buildB(cb ^ 1, cb ^ 1);      // B(y+1) from SL[cb^1]

    // store previous row (RED[cb^1] written last iter, barrier-separated)
    if (d >= 1 && t < NC * XCH) {
      const int c = t >> 5;
      const int xl = t & 31;
      const float o = RED[cb ^ 1][c][0][xl] + RED[cb ^ 1][c][1][xl] +
                      RED[cb ^ 1][c][2][xl] + RED[cb ^ 1][c][3][xl];
      out[((size_t)(b * NC + c) * HH + (y - 1)) * WW + x0 + xl] = o;
    }

    __syncthreads();
    vw_cur[0] = vw_next[0]; vw_cur[1] = vw_next[1];
    vw_cur[2] = vw_next[2]; vw_cur[3] = vw_next[3];
  }

  // epilogue: store last row from RED[1]
  if (t < NC * XCH) {
    const int c = t >> 5;
    const int xl = t & 31;
    const float o = RED[1][c][0][xl] + RED[1][c][1][xl] +
                    RED[1][c][2][xl] + RED[1][c][3][xl];
    out[((size_t)(b * NC + c) * HH + (y0 + YR - 1)) * WW + x0 + xl] = o;
  }
}

}  // namespace

extern "C" void kernel_launch(void* const* d_in, const int* in_sizes, int n_in,
                              void* d_out, int out_size, void* d_ws, size_t ws_size,
                              hipStream_t stream) {
  const float* in1 = (const float*)d_in[0];
  const float* in2 = (const float*)d_in[1];
  const float* in3 = (const float*)d_in[2];
  float* out = (float*)d_out;

  dim3 grid(WW / XCH, HH / YR, NB);
  sepconv_mfma<<<grid, NTHREADS, 0, stream>>>(in1, in2, in3, out);
}

// Round 13
// 90.208 us; speedup vs baseline: 1.3778x; 1.2982x over previous
//
#include <hip/hip_runtime.h>
#include <cstdint>

namespace {

typedef _Float16 half2v __attribute__((ext_vector_type(2)));
typedef _Float16 half8 __attribute__((ext_vector_type(8)));
typedef float f32x4 __attribute__((ext_vector_type(4)));
typedef unsigned int u32x4 __attribute__((ext_vector_type(4)));

constexpr int KFS = 51;
constexpr int NB = 2, NC = 3, HH = 512, WW = 512;
constexpr int HP = HH + KFS - 1;   // 562
constexpr int WP = WW + KFS - 1;   // 562
constexpr size_t VSTR = (size_t)HH * WW;

constexpr int XCH = 32;              // output cols per block (2 n-tiles)
constexpr int YR = 8;                // output rows per block
constexpr int NTHREADS = 512;        // 8 waves = 4 m-tiles x 2 n-tiles
constexpr int NROWS = YR + 64 - 1;   // 71 staged in1 rows
constexpr int AFP = NROWS * 4;       // dw per (c,ks,lq) A plane (284)
constexpr int ASZ = NC * 3 * 4 * AFP;  // 10224 dw (40.9 KB)
constexpr int BFP = 32 * 4;          // dw per (ks,lq) B plane (128)
constexpr int BSZ = 3 * 4 * BFP;     // 1536 dw per buffer (6 KB)
constexpr int SSTR = 54;             // h-slab per-n stride; j at slot 1+j; guards 0 & 52
constexpr int SLN = KFS * 32;        // 1632 slab elements

__device__ __forceinline__ uint32_t pack2(float a, float b) {
  half2v p;
  p.x = (_Float16)a;  // RNE
  p.y = (_Float16)b;
  return __builtin_bit_cast(uint32_t, p);
}

__global__ __launch_bounds__(NTHREADS, 2)
void sepconv_mfma(const float* __restrict__ in1, const float* __restrict__ in2,
                  const float* __restrict__ in3, float* __restrict__ out) {
  // Fragment-major layouts: a b128 fragment read is base + row*16B ->
  // consecutive rows hit consecutive 16B slots (<=2-way banks, free).
  __shared__ __align__(16) uint32_t ALDS[ASZ];      // A[c][ks][lq][row][4dw]
  __shared__ __align__(16) uint32_t BLDS[2 * BSZ];  // B[buf][ks][lq][n][4dw]
  __shared__ float SL[2][32 * SSTR];                // h-slab dbuf (13.8 KB)
  __shared__ float RED[2][NC][4][XCH];              // dbuf (3 KB)

  const int t = threadIdx.x;
  const int lane = t & 63;
  const int wave = t >> 6;
  const int mt = wave & 3;   // m-tile
  const int nt = wave >> 2;  // n-tile
  const int l15 = lane & 15;
  const int lq = lane >> 4;  // k-group (0..3)

  const int x0 = blockIdx.x * XCH;
  const int y0 = blockIdx.y * YR;
  const int b = blockIdx.z;

  const float* in1b = in1 + (size_t)b * NC * HP * WP;
  const float* v2 = in2 + (size_t)b * KFS * VSTR;
  const float* h3 = in3 + (size_t)b * KFS * VSTR;

  // ---- helpers -------------------------------------------------------------
  // Full B rebuild: B[n][k] = h[k-n, y, x0+n]; out-of-band -> 0 via guard slots.
  auto buildB = [&](int sb, int bb) {
    #pragma unroll
    for (int s = 0; s < 3; ++s) {
      const int u = t + s * NTHREADS;           // u < 1536 always
      const int e2 = u & 3;
      const int n = (u >> 2) & 31;
      const int w = u >> 7;                      // ks*4 + lq
      const int j0 = (w >> 2) * 32 + (w & 3) * 8 + 2 * e2 - n;
      const float* sp = &SL[sb][n * SSTR + 1];
      const int ja = min(max(j0, -1), KFS);      // guards: -1 -> slot 0, 51 -> slot 52
      const int jb = min(max(j0 + 1, -1), KFS);
      BLDS[bb * BSZ + u] = pack2(sp[ja], sp[jb]);
    }
  };

  auto loadVW = [&](int y, float (&vw)[4]) {
    const int xg = x0 + nt * 16 + l15;
    #pragma unroll
    for (int r = 0; r < 4; ++r) {
      const int m = mt * 16 + lq * 4 + r;
      vw[r] = (m < KFS) ? v2[(size_t)m * VSTR + (size_t)y * WW + xg] : 0.f;
    }
  };

  // ---- prologue ------------------------------------------------------------
  // Slab guard slots (both buffers; data writes cover slots 1..51 only).
  if (t < 64) {
    const int sb = t >> 5, n = t & 31;
    SL[sb][n * SSTR] = 0.f;
    SL[sb][n * SSTR + 52] = 0.f;
  }
  // Stage A once, fragment-major: dw u = (((c*3+ks)*4+lq)*NROWS + r)*4 + e2.
  for (int u = t; u < ASZ; u += NTHREADS) {
    const int e2 = u & 3;
    const int v = u >> 2;
    const int r = v % NROWS;
    const int w = v / NROWS;                 // (c*3+ks)*4 + lq
    const int lqi = w & 3;
    const int cks = w >> 2;                  // c*3 + ks
    const int ks = cks % 3;
    const int c = cks / 3;
    const int k0 = ks * 32 + lqi * 8 + 2 * e2;   // half index (even)
    const int row = min(y0 + r, HP - 1);         // clamped rows weight-zeroed
    float2 g = make_float2(0.f, 0.f);
    if (k0 < 82)
      g = *reinterpret_cast<const float2*>(in1b + ((size_t)c * HP + row) * WP + x0 + k0);
    ALDS[u] = pack2(g.x, g.y);
  }
  // Slab for y0 and y0+1 (direct: prologue latency is amortized).
  for (int u = t; u < SLN; u += NTHREADS) {
    const int j = u >> 5, n = u & 31;
    SL[0][n * SSTR + 1 + j] = h3[(size_t)j * VSTR + (size_t)y0 * WW + x0 + n];
  }
  for (int u = t; u < SLN; u += NTHREADS) {
    const int j = u >> 5, n = u & 31;
    SL[1][n * SSTR + 1 + j] = h3[(size_t)j * VSTR + (size_t)(y0 + 1) * WW + x0 + n];
  }
  float vw_cur[4];
  loadVW(y0, vw_cur);
  __syncthreads();                 // A, slabs, guards ready

  buildB(0, 0);                    // B(y0) -> BLDS[0]
  __syncthreads();

  // ---- main loop: one barrier per dy ---------------------------------------
  #pragma unroll 1
  for (int d = 0; d < YR; ++d) {
    const int y = y0 + d;
    const int cb = d & 1;

    // T14 issue-early: slab loads for y+2 into regs (written before barrier).
    float hreg[4];
    const bool do_slab = (d + 2 < YR);
    if (do_slab) {
      #pragma unroll
      for (int s = 0; s < 4; ++s) {
        const int u = t + s * NTHREADS;
        if (u < SLN) {
          const int j = u >> 5, n = u & 31;
          hreg[s] = h3[(size_t)j * VSTR + (size_t)(y + 2) * WW + x0 + n];
        }
      }
    }

    // B fragments (b128, fragment-major: base + n*16B)
    u32x4 bf[3];
    #pragma unroll
    for (int ks = 0; ks < 3; ++ks)
      bf[ks] = *reinterpret_cast<const u32x4*>(
          &BLDS[cb * BSZ + (ks * 4 + lq) * BFP + (nt * 16 + l15) * 4]);

    // prefetch v-weights for next dy (register-carried across the barrier)
    float vw_next[4];
    if (d + 1 < YR) loadVW(y + 1, vw_next);

    // A fragments + MFMA (A row = d + m)
    float psum[NC];
    #pragma unroll
    for (int c = 0; c < NC; ++c) {
      f32x4 acc = {0.f, 0.f, 0.f, 0.f};
      #pragma unroll
      for (int ks = 0; ks < 3; ++ks) {
        const u32x4 af = *reinterpret_cast<const u32x4*>(
            &ALDS[((c * 3 + ks) * 4 + lq) * AFP + (d + mt * 16 + l15) * 4]);
        acc = __builtin_amdgcn_mfma_f32_16x16x32_f16(
            __builtin_bit_cast(half8, af), __builtin_bit_cast(half8, bf[ks]),
            acc, 0, 0, 0);
      }
      float p = acc[0] * vw_cur[0];
      p = fmaf(acc[1], vw_cur[1], p);
      p = fmaf(acc[2], vw_cur[2], p);
      p = fmaf(acc[3], vw_cur[3], p);
      psum[c] = p;
    }

    // Column-reduce the fragment's 4 row-quarters -> RED[cb]
    #pragma unroll
    for (int c = 0; c < NC; ++c) {
      float p = psum[c];
      p += __shfl_xor(p, 16);
      p += __shfl_xor(p, 32);
      if (lane < 16) RED[cb][c][mt][nt * 16 + l15] = p;
    }

    // Build B(y+1) from SL[cb^1] (staged 2 iterations ago / prologue).
    if (d + 1 < YR) buildB(cb ^ 1, cb ^ 1);

    // Store previous row (RED[cb^1] written last iteration).
    if (d >= 1 && t < NC * XCH) {
      const int c = t >> 5;
      const int xl = t & 31;
      const float o = RED[cb ^ 1][c][0][xl] + RED[cb ^ 1][c][1][xl] +
                      RED[cb ^ 1][c][2][xl] + RED[cb ^ 1][c][3][xl];
      out[((size_t)(b * NC + c) * HH + (y - 1)) * WW + x0 + xl] = o;
    }

    // T14 write-late: slab writes (vmcnt covered by the whole body above).
    if (do_slab) {
      #pragma unroll
      for (int s = 0; s < 4; ++s) {
        const int u = t + s * NTHREADS;
        if (u < SLN) {
          const int j = u >> 5, n = u & 31;
          SL[cb][n * SSTR + 1 + j] = hreg[s];
        }
      }
    }

    __syncthreads();
    vw_cur[0] = vw_next[0]; vw_cur[1] = vw_next[1];
    vw_cur[2] = vw_next[2]; vw_cur[3] = vw_next[3];
  }

  // epilogue: store last row from RED[(YR-1)&1] = RED[1]
  if (t < NC * XCH) {
    const int c = t >> 5;
    const int xl = t & 31;
    const float o = RED[1][c][0][xl] + RED[1][c][1][xl] +
                    RED[1][c][2][xl] + RED[1][c][3][xl];
    out[((size_t)(b * NC + c) * HH + (y0 + YR - 1)) * WW + x0 + xl] = o;
  }
}

}  // namespace

extern "C" void kernel_launch(void* const* d_in, const int* in_sizes, int n_in,
                              void* d_out, int out_size, void* d_ws, size_t ws_size,
                              hipStream_t stream) {
  const float* in1 = (const float*)d_in[0];
  const float* in2 = (const float*)d_in[1];
  const float* in3 = (const float*)d_in[2];
  float* out = (float*)d_out;

  dim3 grid(WW / XCH, HH / YR, NB);
  sepconv_mfma<<<grid, NTHREADS, 0, stream>>>(in1, in2, in3, out);
}

// Round 14
// 83.494 us; speedup vs baseline: 1.4886x; 1.0804x over previous
//
#include <hip/hip_runtime.h>
#include <cstdint>

namespace {

typedef _Float16 half2v __attribute__((ext_vector_type(2)));
typedef _Float16 half8 __attribute__((ext_vector_type(8)));
typedef float f32x4 __attribute__((ext_vector_type(4)));
typedef unsigned int u32x4 __attribute__((ext_vector_type(4)));

constexpr int KFS = 51;
constexpr int NB = 2, NC = 3, HH = 512, WW = 512;
constexpr int HP = HH + KFS - 1;   // 562
constexpr int WP = WW + KFS - 1;   // 562
constexpr size_t VSTR = (size_t)HH * WW;

constexpr int XCH = 32;              // output cols per block
constexpr int YR = 8;                // output rows per block (1 per wave)
constexpr int NTHREADS = 512;        // 8 waves
constexpr int NROWS = YR + 64 - 1;   // 71 staged in1 rows
constexpr int AFP = NROWS * 4;       // dw per (c,ks,lq) A plane (284)
constexpr int ASZ = NC * 3 * 4 * AFP;  // 10224 dw (40.9 KB)
constexpr int SS = 26;               // f16-pair slots per (y,n): j-pairs 0..50
constexpr int SLSZ = YR * SS * 32;   // 6656 dw (26.6 KB), layout [y][s][n]

__device__ __forceinline__ uint32_t pack2(float a, float b) {
  half2v p;
  p.x = (_Float16)a;  // RNE
  p.y = (_Float16)b;
  return __builtin_bit_cast(uint32_t, p);
}

__global__ __launch_bounds__(NTHREADS, 4)
void sepconv_mfma(const float* __restrict__ in1, const float* __restrict__ in2,
                  const float* __restrict__ in3, float* __restrict__ out) {
  __shared__ __align__(16) uint32_t ALDS[ASZ];  // A[c][ks][lq][row][4dw], fragment-major
  __shared__ uint32_t SLAB[SLSZ];               // h pairs [y][s][n]; bank = n

  const int t = threadIdx.x;
  const int lane = t & 63;
  const int w = t >> 6;      // wave id == row offset within tile
  const int l15 = lane & 15;
  const int lq = lane >> 4;  // k-group (0..3)

  const int x0 = blockIdx.x * XCH;
  const int y0 = blockIdx.y * YR;
  const int b = blockIdx.z;

  const float* in1b = in1 + (size_t)b * NC * HP * WP;
  const float* v2 = in2 + (size_t)b * KFS * VSTR;
  const float* h3 = in3 + (size_t)b * KFS * VSTR;

  // ---- prologue (once; only barrier in the kernel) -------------------------
  // Stage A fragment-major: dw u = (((c*3+ks)*4+lq)*NROWS + r)*4 + e2.
  for (int u = t; u < ASZ; u += NTHREADS) {
    const int e2 = u & 3;
    const int v = u >> 2;
    const int r = v % NROWS;
    const int ww = v / NROWS;                // (c*3+ks)*4 + lq
    const int lqi = ww & 3;
    const int cks = ww >> 2;
    const int ks = cks % 3;
    const int c = cks / 3;
    const int k0 = ks * 32 + lqi * 8 + 2 * e2;
    const int row = min(y0 + r, HP - 1);     // clamped rows are weight-zeroed
    float2 g = make_float2(0.f, 0.f);
    if (k0 < 82)
      g = *reinterpret_cast<const float2*>(in1b + ((size_t)c * HP + row) * WP + x0 + k0);
    ALDS[u] = pack2(g.x, g.y);
  }
  // Stage h-slab: SLAB[(yy*SS+s)*32+n] = pack(h[2s,y0+yy,x0+n], h[2s+1,...]).
  for (int q = t; q < SLSZ; q += NTHREADS) {
    const int n = q & 31;                    // lane-consecutive -> coalesced
    const int s = (q >> 5) % SS;
    const int yy = q / (SS * 32);
    const float* hp = h3 + (size_t)(y0 + yy) * WW + x0 + n;
    const float a = hp[(size_t)(2 * s) * VSTR];
    const float bq = (2 * s + 1 < KFS) ? hp[(size_t)(2 * s + 1) * VSTR] : 0.f;
    SLAB[q] = pack2(a, bq);
  }
  __syncthreads();

  // ---- main: this wave owns output row y = y0 + w; no further barriers ----
  const int y = y0 + w;
  const uint32_t* SLy = &SLAB[w * SS * 32];
  const int sh = (l15 & 1) * 16;  // band shift parity: n = nt*16+l15, nt*16 even

  #pragma unroll
  for (int nt = 0; nt < 2; ++nt) {
    const int n = nt * 16 + l15;

    // Build B fragments in registers: B[k][n] = h[k-n], k = ks*32+lq*8+e.
    // Pairs (h[j0+2u], h[j0+2u+1]) via masked slab reads + alignbit funnel.
    u32x4 bf[3];
    #pragma unroll
    for (int ks = 0; ks < 3; ++ks) {
      const int j0 = ks * 32 + lq * 8 - n;
      const int sB = j0 >> 1;                // arithmetic floor
      uint32_t P[5];
      #pragma unroll
      for (int u = 0; u < 5; ++u) {
        const int s = sB + u;
        const int sc = min(max(s, 0), SS - 1);
        const uint32_t pv = SLy[sc * 32 + n];
        P[u] = ((unsigned)s <= (unsigned)(SS - 1)) ? pv : 0u;
      }
      u32x4 f;
      f.x = __builtin_amdgcn_alignbit(P[1], P[0], sh);
      f.y = __builtin_amdgcn_alignbit(P[2], P[1], sh);
      f.z = __builtin_amdgcn_alignbit(P[3], P[2], sh);
      f.w = __builtin_amdgcn_alignbit(P[4], P[3], sh);
      bf[ks] = f;
    }

    const int xg = x0 + n;
    float ps[NC] = {0.f, 0.f, 0.f};

    #pragma unroll
    for (int mt = 0; mt < 4; ++mt) {
      // v weights for this mt (C fragment: col=l15, row=lq*4+r)
      float vw[4];
      #pragma unroll
      for (int r = 0; r < 4; ++r) {
        const int m = mt * 16 + lq * 4 + r;
        vw[r] = (m < KFS) ? v2[(size_t)m * VSTR + (size_t)y * WW + xg] : 0.f;
      }
      #pragma unroll
      for (int c = 0; c < NC; ++c) {
        f32x4 acc = {0.f, 0.f, 0.f, 0.f};
        #pragma unroll
        for (int ks = 0; ks < 3; ++ks) {
          const u32x4 af = *reinterpret_cast<const u32x4*>(
              &ALDS[((c * 3 + ks) * 4 + lq) * AFP + (w + mt * 16 + l15) * 4]);
          acc = __builtin_amdgcn_mfma_f32_16x16x32_f16(
              __builtin_bit_cast(half8, af), __builtin_bit_cast(half8, bf[ks]),
              acc, 0, 0, 0);
        }
        float p = acc[0] * vw[0];
        p = fmaf(acc[1], vw[1], p);
        p = fmaf(acc[2], vw[2], p);
        p = fmaf(acc[3], vw[3], p);
        ps[c] += p;
      }
    }

    // Wave-local m-reduce (across lq quarters) + direct store.
    #pragma unroll
    for (int c = 0; c < NC; ++c) {
      float p = ps[c];
      p += __shfl_xor(p, 16);
      p += __shfl_xor(p, 32);
      if (lane < 16)
        out[((size_t)(b * NC + c) * HH + y) * WW + xg] = p;
    }
  }
}

}  // namespace

extern "C" void kernel_launch(void* const* d_in, const int* in_sizes, int n_in,
                              void* d_out, int out_size, void* d_ws, size_t ws_size,
                              hipStream_t stream) {
  const float* in1 = (const float*)d_in[0];
  const float* in2 = (const float*)d_in[1];
  const float* in3 = (const float*)d_in[2];
  float* out = (float*)d_out;

  dim3 grid(WW / XCH, HH / YR, NB);
  sepconv_mfma<<<grid, NTHREADS, 0, stream>>>(in1, in2, in3, out);
}

// Round 15
// 80.222 us; speedup vs baseline: 1.5493x; 1.0408x over previous
//
#include <hip/hip_runtime.h>
#include <cstdint>

namespace {

typedef _Float16 half2v __attribute__((ext_vector_type(2)));
typedef _Float16 half8 __attribute__((ext_vector_type(8)));
typedef float f32x4 __attribute__((ext_vector_type(4)));
typedef unsigned int u32x4 __attribute__((ext_vector_type(4)));

constexpr int KFS = 51;
constexpr int NB = 2, NC = 3, HH = 512, WW = 512;
constexpr int HP = HH + KFS - 1;   // 562
constexpr int WP = WW + KFS - 1;   // 562
constexpr size_t VSTR = (size_t)HH * WW;

constexpr int XCH = 32;              // output cols per block
constexpr int YR = 8;                // output rows per block (1 per wave)
constexpr int NTHREADS = 512;        // 8 waves
constexpr int NROWS = YR + 64 - 1;   // 71 staged in1 rows
constexpr int AFP = NROWS * 4;       // dw per (c,ks,lq) A plane (284)
constexpr int ASZ = NC * 3 * 4 * AFP;  // 10224 dw (40.9 KB)
constexpr int AV = NC * 3 * 4 * NROWS; // 2556 v-units
constexpr int SS = 26;               // f16-pair slots per (y,n)
constexpr int SLSZ = YR * SS * 32;   // 6656 dw (26.6 KB), layout [y][s][n]

__device__ __forceinline__ uint32_t pack2(float a, float b) {
  half2v p;
  p.x = (_Float16)a;  // RNE
  p.y = (_Float16)b;
  return __builtin_bit_cast(uint32_t, p);
}

__global__ __launch_bounds__(NTHREADS, 4)
void sepconv_mfma(const float* __restrict__ in1, const float* __restrict__ in2,
                  const float* __restrict__ in3, float* __restrict__ out) {
  __shared__ __align__(16) uint32_t ALDS[ASZ];  // A[c][ks][lq][row][4dw], fragment-major
  __shared__ uint32_t SLAB[SLSZ];               // h pairs [y][s][n]; bank = n

  const int t = threadIdx.x;
  const int lane = t & 63;
  const int w = t >> 6;      // wave id == row offset within tile
  const int l15 = lane & 15;
  const int lq = lane >> 4;  // k-group (0..3)

  const int x0 = blockIdx.x * XCH;
  const int y0 = blockIdx.y * YR;
  const int b = blockIdx.z;

  const float* in1b = in1 + (size_t)b * NC * HP * WP;
  const float* v2 = in2 + (size_t)b * KFS * VSTR;
  const float* h3 = in3 + (size_t)b * KFS * VSTR;
  const int y = y0 + w;

  // ---- v-weight hoist: issued BEFORE the barrier; the barrier's vmcnt drain
  // completes them during staging (zero exposed latency), held in 32 VGPRs.
  float vw[4][2][4];
  #pragma unroll
  for (int mt = 0; mt < 4; ++mt)
    #pragma unroll
    for (int nt = 0; nt < 2; ++nt)
      #pragma unroll
      for (int r = 0; r < 4; ++r) {
        const int m = mt * 16 + lq * 4 + r;
        vw[mt][nt][r] = (m < KFS)
            ? v2[(size_t)m * VSTR + (size_t)y * WW + x0 + nt * 16 + l15] : 0.f;
      }

  // ---- Stage A fragment-major (incremental indexing, no div/mod per step).
  {
    const int e2 = t & 3;
    int v = t >> 2;                       // 0..127
    int ww = (v >= NROWS) ? 1 : 0;
    int r = v - ww * NROWS;
    #pragma unroll 1
    for (int s = 0; s < 20; ++s) {
      if (v < AV) {
        const int lqi = ww & 3;
        const int cks = ww >> 2;          // 0..8
        const int c = cks / 3;
        const int ks = cks - 3 * c;
        const int k0 = ks * 32 + lqi * 8 + 2 * e2;
        const int row = min(y0 + r, HP - 1);  // clamped rows weight-zeroed
        float2 g = make_float2(0.f, 0.f);
        if (k0 < 82)
          g = *reinterpret_cast<const float2*>(in1b + ((size_t)c * HP + row) * WP + x0 + k0);
        ALDS[(v << 2) | e2] = pack2(g.x, g.y);
      }
      v += 128;
      r += 57; ww += 1;
      if (r >= NROWS) { r -= NROWS; ww += 1; }
    }
  }
  // ---- Stage h-slab (13 exact steps; incremental (sidx,yy)).
  {
    const int n = t & 31;
    int sidx = t >> 5;  // 0..15 (< SS)
    int yy = 0;
    #pragma unroll 1
    for (int s13 = 0; s13 < 13; ++s13) {
      const float* hp = h3 + (size_t)(y0 + yy) * WW + x0 + n;
      const float a = hp[(size_t)(2 * sidx) * VSTR];
      const float bq = (2 * sidx + 1 < KFS) ? hp[(size_t)(2 * sidx + 1) * VSTR] : 0.f;
      SLAB[(yy * SS + sidx) * 32 + n] = pack2(a, bq);
      sidx += 16;
      if (sidx >= SS) { sidx -= SS; ++yy; }
    }
  }
  __syncthreads();

  // ---- main: wave owns row y; no further barriers -------------------------
  const uint32_t* SLy = &SLAB[w * SS * 32];
  const int sh = (l15 & 1) * 16;

  // B fragments for both n-tiles, in registers (24 VGPR).
  u32x4 bf[2][3];
  #pragma unroll
  for (int nt = 0; nt < 2; ++nt) {
    const int n = nt * 16 + l15;
    #pragma unroll
    for (int ks = 0; ks < 3; ++ks) {
      const int j0 = ks * 32 + lq * 8 - n;
      const int sB = j0 >> 1;
      uint32_t P[5];
      #pragma unroll
      for (int u = 0; u < 5; ++u) {
        const int s = sB + u;
        const int sc = min(max(s, 0), SS - 1);
        const uint32_t pv = SLy[sc * 32 + n];
        P[u] = ((unsigned)s <= (unsigned)(SS - 1)) ? pv : 0u;
      }
      u32x4 f;
      f.x = __builtin_amdgcn_alignbit(P[1], P[0], sh);
      f.y = __builtin_amdgcn_alignbit(P[2], P[1], sh);
      f.z = __builtin_amdgcn_alignbit(P[3], P[2], sh);
      f.w = __builtin_amdgcn_alignbit(P[4], P[3], sh);
      bf[nt][ks] = f;
    }
  }

  float ps[2][NC] = {};
  #pragma unroll
  for (int mt = 0; mt < 4; ++mt) {
    #pragma unroll
    for (int c = 0; c < NC; ++c) {
      // A fragments loaded ONCE, shared by both n-tiles.
      u32x4 af[3];
      #pragma unroll
      for (int ks = 0; ks < 3; ++ks)
        af[ks] = *reinterpret_cast<const u32x4*>(
            &ALDS[((c * 3 + ks) * 4 + lq) * AFP + (w + mt * 16 + l15) * 4]);
      #pragma unroll
      for (int nt = 0; nt < 2; ++nt) {
        f32x4 acc = {0.f, 0.f, 0.f, 0.f};
        #pragma unroll
        for (int ks = 0; ks < 3; ++ks)
          acc = __builtin_amdgcn_mfma_f32_16x16x32_f16(
              __builtin_bit_cast(half8, af[ks]),
              __builtin_bit_cast(half8, bf[nt][ks]), acc, 0, 0, 0);
        float p = acc[0] * vw[mt][nt][0];
        p = fmaf(acc[1], vw[mt][nt][1], p);
        p = fmaf(acc[2], vw[mt][nt][2], p);
        p = fmaf(acc[3], vw[mt][nt][3], p);
        ps[nt][c] += p;
      }
    }
  }

  // Wave-local m-reduce + merged 32-lane store (one 128B store per c).
  #pragma unroll
  for (int c = 0; c < NC; ++c) {
    float pa = ps[0][c];
    pa += __shfl_xor(pa, 16);
    pa += __shfl_xor(pa, 32);
    float pb = ps[1][c];
    pb += __shfl_xor(pb, 16);
    pb += __shfl_xor(pb, 32);
    const float po = (lane < 16) ? pa : pb;
    if (lane < 32)
      out[((size_t)(b * NC + c) * HH + y) * WW + x0 + lane] = po;
  }
}

}  // namespace

extern "C" void kernel_launch(void* const* d_in, const int* in_sizes, int n_in,
                              void* d_out, int out_size, void* d_ws, size_t ws_size,
                              hipStream_t stream) {
  const float* in1 = (const float*)d_in[0];
  const float* in2 = (const float*)d_in[1];
  const float* in3 = (const float*)d_in[2];
  float* out = (float*)d_out;

  dim3 grid(WW / XCH, HH / YR, NB);
  sepconv_mfma<<<grid, NTHREADS, 0, stream>>>(in1, in2, in3, out);
}

// Round 16
// 65.367 us; speedup vs baseline: 1.9014x; 1.2273x over previous
//
#include <hip/hip_runtime.h>
#include <cstdint>

namespace {

typedef _Float16 half2v __attribute__((ext_vector_type(2)));
typedef _Float16 half8 __attribute__((ext_vector_type(8)));
typedef float f32x4 __attribute__((ext_vector_type(4)));
typedef unsigned int u32x4 __attribute__((ext_vector_type(4)));

constexpr int KFS = 51;
constexpr int NB = 2, NC = 3, HH = 512, WW = 512;
constexpr int HP = HH + KFS - 1;   // 562
constexpr int WP = WW + KFS - 1;   // 562
constexpr size_t VSTR = (size_t)HH * WW;

constexpr int XCH = 32;              // output cols per block
constexpr int YR = 8;                // output rows per block (1 per wave)
constexpr int NTHREADS = 512;        // 8 waves
constexpr int NROWS = YR + 64 - 1;   // 71 staged in1 rows
constexpr int AFP = NROWS * 4;       // dw per (c,ks,lq) A plane (284)
constexpr int ASZ = NC * 3 * 4 * AFP;  // 10224 dw (40.9 KB)
constexpr int AV = NC * 3 * 4 * NROWS; // 2556 v-units
constexpr int SS = 26;               // f16-pair slots per (y,n)
constexpr int SLROW = SS + 2;        // 28: zero guards at slot 0 and 27, data 1..26
constexpr int SLSZ = YR * SLROW * 32;  // 7168 dw (28.7 KB), layout [y][slot][n]

__device__ __forceinline__ uint32_t pack2(float a, float b) {
  half2v p;
  p.x = (_Float16)a;  // RNE
  p.y = (_Float16)b;
  return __builtin_bit_cast(uint32_t, p);
}

__global__ __launch_bounds__(NTHREADS, 4)
void sepconv_mfma(const float* __restrict__ in1, const float* __restrict__ in2,
                  const float* __restrict__ in3, float* __restrict__ out) {
  __shared__ __align__(16) uint32_t ALDS[ASZ];  // A[c][ks][lq][row][4dw], fragment-major
  __shared__ uint32_t SLAB[SLSZ];               // h pairs, per-wave row; bank = n

  const int t = threadIdx.x;
  const int lane = t & 63;
  const int w = t >> 6;      // wave id == row offset within tile
  const int l15 = lane & 15;
  const int lq = lane >> 4;  // k-group (0..3)

  const int x0 = blockIdx.x * XCH;
  const int y0 = blockIdx.y * YR;
  const int b = blockIdx.z;

  const float* in1b = in1 + (size_t)b * NC * HP * WP;
  const float* v2 = in2 + (size_t)b * KFS * VSTR;
  const float* h3 = in3 + (size_t)b * KFS * VSTR;
  const int y = y0 + w;

  // ---- issue vw loads (32, live until main loop) ---------------------------
  float vw[4][2][4];
  #pragma unroll
  for (int mt = 0; mt < 4; ++mt)
    #pragma unroll
    for (int nt = 0; nt < 2; ++nt)
      #pragma unroll
      for (int r = 0; r < 4; ++r) {
        const int m = mt * 16 + lq * 4 + r;
        vw[mt][nt][r] = (m < KFS)
            ? v2[(size_t)m * VSTR + (size_t)y * WW + x0 + nt * 16 + l15] : 0.f;
      }

  // ---- issue wave-local slab loads (26, into regs) -------------------------
  uint32_t* SLW = &SLAB[w * SLROW * 32];
  const int sn = lane & 31;
  const int shf = lane >> 5;  // 0 or 1
  float sa[13], sb[13];
  {
    const float* hp = h3 + (size_t)y * WW + x0 + sn;
    #pragma unroll
    for (int i = 0; i < 13; ++i) {
      const int s = 2 * i + shf;                 // s = 0..25, each once
      sa[i] = hp[(size_t)(2 * s) * VSTR];
      sb[i] = (2 * s + 1 < KFS) ? hp[(size_t)(2 * s + 1) * VSTR] : 0.f;
    }
  }

  // ---- A stage: 2 batches of 10 (issue-all, then write-all) ----------------
  const int e2 = t & 3;
  {
    int v = t >> 2;
    int ww2 = (v >= NROWS) ? 1 : 0;
    int r = v - ww2 * NROWS;
    float2 ga[10];
    #pragma unroll
    for (int half = 0; half < 2; ++half) {
      #pragma unroll
      for (int s = 0; s < 10; ++s) {
        float2 g = make_float2(0.f, 0.f);
        if (v < AV) {
          const int lqi = ww2 & 3;
          const int cks = ww2 >> 2;              // 0..8
          const int c = cks / 3;
          const int ks = cks - 3 * c;
          const int k0 = ks * 32 + lqi * 8 + 2 * e2;
          const int row = min(y0 + r, HP - 1);   // clamped rows weight-zeroed
          if (k0 < 82)
            g = *reinterpret_cast<const float2*>(
                in1b + ((size_t)c * HP + row) * WP + x0 + k0);
        }
        ga[s] = g;
        v += 128; r += 57; ww2 += 1;
        if (r >= NROWS) { r -= NROWS; ++ww2; }
      }
      #pragma unroll
      for (int s = 0; s < 10; ++s) {
        const int vv = (t >> 2) + 128 * (half * 10 + s);
        if (vv < AV) ALDS[(vv << 2) | e2] = pack2(ga[s].x, ga[s].y);
      }
    }
  }

  // ---- write slab (guards + data) ------------------------------------------
  SLW[(shf ? (SLROW - 1) : 0) * 32 + sn] = 0u;   // zero guard slots 0 and 27
  #pragma unroll
  for (int i = 0; i < 13; ++i) {
    const int s = 2 * i + shf;
    SLW[(s + 1) * 32 + sn] = pack2(sa[i], sb[i]);
  }
  __syncthreads();

  // ---- B fragments in registers (guard slots kill the zero-selects) --------
  const uint32_t* SLy = SLW;
  const int sh = (l15 & 1) * 16;
  u32x4 bf[2][3];
  #pragma unroll
  for (int nt = 0; nt < 2; ++nt) {
    const int n = nt * 16 + l15;
    #pragma unroll
    for (int ks = 0; ks < 3; ++ks) {
      const int j0 = ks * 32 + lq * 8 - n;
      const int sB = j0 >> 1;
      uint32_t P[5];
      #pragma unroll
      for (int u = 0; u < 5; ++u) {
        const int sc = min(max(sB + u, -1), SS) + 1;  // 0..27; 0 & 27 are zeros
        P[u] = SLy[sc * 32 + n];
      }
      u32x4 f;
      f.x = __builtin_amdgcn_alignbit(P[1], P[0], sh);
      f.y = __builtin_amdgcn_alignbit(P[2], P[1], sh);
      f.z = __builtin_amdgcn_alignbit(P[3], P[2], sh);
      f.w = __builtin_amdgcn_alignbit(P[4], P[3], sh);
      bf[nt][ks] = f;
    }
  }

  // ---- main MFMA loop -------------------------------------------------------
  float ps[2][NC] = {};
  #pragma unroll
  for (int mt = 0; mt < 4; ++mt) {
    #pragma unroll
    for (int c = 0; c < NC; ++c) {
      u32x4 af[3];
      #pragma unroll
      for (int ks = 0; ks < 3; ++ks)
        af[ks] = *reinterpret_cast<const u32x4*>(
            &ALDS[((c * 3 + ks) * 4 + lq) * AFP + (w + mt * 16 + l15) * 4]);
      #pragma unroll
      for (int nt = 0; nt < 2; ++nt) {
        f32x4 acc = {0.f, 0.f, 0.f, 0.f};
        #pragma unroll
        for (int ks = 0; ks < 3; ++ks)
          acc = __builtin_amdgcn_mfma_f32_16x16x32_f16(
              __builtin_bit_cast(half8, af[ks]),
              __builtin_bit_cast(half8, bf[nt][ks]), acc, 0, 0, 0);
        float p = acc[0] * vw[mt][nt][0];
        p = fmaf(acc[1], vw[mt][nt][1], p);
        p = fmaf(acc[2], vw[mt][nt][2], p);
        p = fmaf(acc[3], vw[mt][nt][3], p);
        ps[nt][c] += p;
      }
    }
  }

  // ---- wave-local m-reduce + merged 32-lane store ---------------------------
  #pragma unroll
  for (int c = 0; c < NC; ++c) {
    float pa = ps[0][c];
    pa += __shfl_xor(pa, 16);
    pa += __shfl_xor(pa, 32);
    float pb = ps[1][c];
    pb += __shfl_xor(pb, 16);
    pb += __shfl_xor(pb, 32);
    const float po = (lane < 16) ? pa : pb;
    if (lane < 32)
      out[((size_t)(b * NC + c) * HH + y) * WW + x0 + lane] = po;
  }
}

}  // namespace

extern "C" void kernel_launch(void* const* d_in, const int* in_sizes, int n_in,
                              void* d_out, int out_size, void* d_ws, size_t ws_size,
                              hipStream_t stream) {
  const float* in1 = (const float*)d_in[0];
  const float* in2 = (const float*)d_in[1];
  const float* in3 = (const float*)d_in[2];
  float* out = (float*)d_out;

  dim3 grid(WW / XCH, HH / YR, NB);
  sepconv_mfma<<<grid, NTHREADS, 0, stream>>>(in1, in2, in3, out);
}